// Round 2
// baseline (42364.316 us; speedup 1.0000x reference)
//
#include <hip/hip_runtime.h>
#include <hip/hip_bf16.h>

typedef _Float16 f16x8 __attribute__((ext_vector_type(8)));
typedef float f32x4 __attribute__((ext_vector_type(4)));

#define DI static __device__ __forceinline__

constexpr int Bn = 64, Fn = 128, Tn = 1024, Hn = 256, NTn = 11;
constexpr int BT = Bn * Tn;       // 65536
constexpr int Gn = 4 * Hn;        // 1024
constexpr int Sn = 4 * Tn;        // 4096

// ---------------- device global buffers (no d_ws use) ----------------
__device__ __align__(16) _Float16 g_xt_h[BT * Fn];
__device__ __align__(16) _Float16 g_xt_l[BT * Fn];
__device__ __align__(16) _Float16 g_f0_h[BT * 512];
__device__ __align__(16) _Float16 g_f0_l[BT * 512];
__device__ __align__(16) _Float16 g_f1_h[BT * 512];
__device__ __align__(16) _Float16 g_f1_l[BT * 512];
__device__ __align__(16) float    g_xg[(size_t)BT * 2048];   // 512MB, reused per layer
__device__ __align__(16) _Float16 g_whh_h[4 * Gn * Hn];      // fragment-swizzled
__device__ __align__(16) _Float16 g_whh_l[4 * Gn * Hn];
__device__ __align__(16) _Float16 g_wih0_h[2048 * Fn];
__device__ __align__(16) _Float16 g_wih0_l[2048 * Fn];
__device__ __align__(16) _Float16 g_wih1_h[2048 * 512];
__device__ __align__(16) _Float16 g_wih1_l[2048 * 512];
__device__ __align__(16) _Float16 g_wout_h[48 * 512];
__device__ __align__(16) _Float16 g_wout_l[48 * 512];
__device__ float g_b0[2048], g_b1[2048], g_bo[48];
__device__ float g_em[BT * 44];
__device__ __align__(4) unsigned char g_hist[(size_t)Sn * Bn * NTn];
__device__ int   g_rev[BT];
__device__ float g_llh[Bn];
__device__ int   g_last[Bn];

DI f32x4 mfma_(f16x8 a, f16x8 b, f32x4 c) {
  return __builtin_amdgcn_mfma_f32_16x16x32_f16(a, b, c, 0, 0, 0);
}
DI float sigf(float x) { return 1.f / (1.f + __expf(-x)); }

// ---------------- prep kernels ----------------
__global__ void k_split(const float* __restrict__ src, int which, int off, int n) {
  int i = blockIdx.x * 256 + threadIdx.x;
  if (i >= n) return;
  float v = src[i];
  _Float16 h = (_Float16)v;
  _Float16 l = (_Float16)(v - (float)h);
  _Float16 *H, *L;
  switch (which) {
    case 1:  H = g_wih0_h; L = g_wih0_l; break;
    case 2:  H = g_wih1_h; L = g_wih1_l; break;
    default: H = g_wout_h; L = g_wout_l; break;
  }
  H[off + i] = h; L[off + i] = l;
}

// W_hh -> fragment-contiguous swizzle: idx = (((nt*8 + kc)*64 + lane)*8 + j)
// holds W[nt*16 + (lane&15)][kc*32 + (lane>>4)*8 + j]
__global__ void k_wswz(const float* __restrict__ w0, const float* __restrict__ w1,
                       const float* __restrict__ w2, const float* __restrict__ w3) {
  int i = blockIdx.x * 256 + threadIdx.x;
  if (i >= 4 * Gn * Hn) return;
  int mat = i >> 18;
  int e = i & 262143;
  int nt = e >> 12, rem = e & 4095;
  int kc = rem >> 9;
  int rem2 = rem & 511;
  int lane = rem2 >> 3, j = rem2 & 7;
  int row = nt * 16 + (lane & 15);
  int col = kc * 32 + (lane >> 4) * 8 + j;
  const float* src = mat == 0 ? w0 : mat == 1 ? w1 : mat == 2 ? w2 : w3;
  float v = src[row * Hn + col];
  _Float16 h = (_Float16)v;
  g_whh_h[i] = h;
  g_whh_l[i] = (_Float16)(v - (float)h);
}

__global__ void k_copy(const float* __restrict__ src, int which, int off, int n) {
  int i = blockIdx.x * 256 + threadIdx.x;
  if (i >= n) return;
  float* D = which == 0 ? g_b0 : which == 1 ? g_b1 : g_bo;
  D[off + i] = src[i];
}

__global__ void k_pad() {
  int i = blockIdx.x * 256 + threadIdx.x;
  if (i < 48 * 512 - 44 * 512) {            // zero pad rows 44..47 of w_out
    g_wout_h[44 * 512 + i] = (_Float16)0.f;
    g_wout_l[44 * 512 + i] = (_Float16)0.f;
  }
  if (i < 4) g_bo[44 + i] = 0.f;
}

__global__ void k_rev(const int* __restrict__ lengths) {
  int i = blockIdx.x * 256 + threadIdx.x;
  if (i >= BT) return;
  int b = i >> 10, t = i & 1023;
  int len = lengths[b];
  int r = (t < len) ? (len - 1 - t) : t;
  g_rev[i] = (b << 10) | r;
}

// x (B,F,T) -> xt rows (b*T+t, d) split to f16 hi/lo
__global__ void k_xpose(const float* __restrict__ x) {
  __shared__ float tile[32][33];
  int t0 = blockIdx.x * 32, d0 = blockIdx.y * 32, b = blockIdx.z;
  int tx = threadIdx.x, ty = threadIdx.y;
  #pragma unroll
  for (int i = 0; i < 4; i++) {
    int d = d0 + ty + i * 8;
    tile[ty + i * 8][tx] = x[((size_t)b * Fn + d) * Tn + t0 + tx];
  }
  __syncthreads();
  #pragma unroll
  for (int i = 0; i < 4; i++) {
    int t = t0 + ty + i * 8;
    float v = tile[tx][ty + i * 8];
    _Float16 h = (_Float16)v;
    size_t o = ((size_t)b * Tn + t) * Fn + d0 + tx;
    g_xt_h[o] = h;
    g_xt_l[o] = (_Float16)(v - (float)h);
  }
}

// ---------------- generic dual-f16 MFMA GEMM ----------------
// SEL: 0 = proj layer0 (A=xt,K=128), 1 = proj layer1 (A=f0,K=512), 2 = emissions (A=f1,N=48->44)
template <int SEL, int NPL>
__global__ __launch_bounds__(256) void k_gemm() {
  constexpr int KD = SEL == 0 ? 128 : 512;
  constexpr int WM = SEL == 2 ? 4 : 2;
  constexpr int WN = SEL == 2 ? 1 : 2;
  constexpr int MW = SEL == 2 ? 2 : 4;
  constexpr int NW = SEL == 2 ? 3 : 4;
  constexpr int LDO = SEL == 2 ? 44 : 2048;
  constexpr int NCOL = SEL == 2 ? 44 : 2048;
  constexpr int NSPLIT = SEL == 2 ? (1 << 30) : 1024;
  const _Float16* Ah = SEL == 0 ? g_xt_h : SEL == 1 ? g_f0_h : g_f1_h;
  const _Float16* Al = SEL == 0 ? g_xt_l : SEL == 1 ? g_f0_l : g_f1_l;
  const _Float16* Bh = SEL == 0 ? g_wih0_h : SEL == 1 ? g_wih1_h : g_wout_h;
  const _Float16* Bl = SEL == 0 ? g_wih0_l : SEL == 1 ? g_wih1_l : g_wout_l;
  const float* bias = SEL == 0 ? g_b0 : SEL == 1 ? g_b1 : g_bo;
  float* out = SEL == 2 ? g_em : g_xg;

  const int lane = threadIdx.x & 63, wv = threadIdx.x >> 6;
  const int wm = wv / WN, wn = wv % WN;
  const int c = lane & 15, q = lane >> 4;
  const int bm0 = blockIdx.x * (WM * MW * 16);
  const int bn0 = blockIdx.y * (WN * NW * 16);
  const bool bw = bn0 >= NSPLIT;   // backward-direction column block -> gathered A rows
  int arow[MW];
  #pragma unroll
  for (int mi = 0; mi < MW; mi++) {
    int r = bm0 + (wm * MW + mi) * 16 + c;
    arow[mi] = bw ? g_rev[r] : r;
  }
  f32x4 acc[MW][NW];
  #pragma unroll
  for (int mi = 0; mi < MW; mi++)
    #pragma unroll
    for (int ni = 0; ni < NW; ni++) acc[mi][ni] = f32x4{0.f, 0.f, 0.f, 0.f};

  for (int kc = 0; kc < KD / 32; kc++) {
    const int k = kc * 32 + q * 8;
    f16x8 ah[MW], al[MW], bh[NW], bl[NW];
    #pragma unroll
    for (int mi = 0; mi < MW; mi++) {
      ah[mi] = *(const f16x8*)(Ah + (size_t)arow[mi] * KD + k);
      if constexpr (NPL > 1) al[mi] = *(const f16x8*)(Al + (size_t)arow[mi] * KD + k);
    }
    #pragma unroll
    for (int ni = 0; ni < NW; ni++) {
      int n = bn0 + (wn * NW + ni) * 16 + c;
      bh[ni] = *(const f16x8*)(Bh + (size_t)n * KD + k);
      if constexpr (NPL > 1) bl[ni] = *(const f16x8*)(Bl + (size_t)n * KD + k);
    }
    #pragma unroll
    for (int mi = 0; mi < MW; mi++)
      #pragma unroll
      for (int ni = 0; ni < NW; ni++) {
        acc[mi][ni] = mfma_(ah[mi], bh[ni], acc[mi][ni]);
        if constexpr (NPL > 1) {
          acc[mi][ni] = mfma_(ah[mi], bl[ni], acc[mi][ni]);
          acc[mi][ni] = mfma_(al[mi], bh[ni], acc[mi][ni]);
        }
      }
  }
  #pragma unroll
  for (int mi = 0; mi < MW; mi++)
    #pragma unroll
    for (int ni = 0; ni < NW; ni++) {
      int col = bn0 + (wn * NW + ni) * 16 + c;
      if (col < NCOL) {
        int row0 = bm0 + (wm * MW + mi) * 16 + q * 4;
        float bv = bias[col];
        #pragma unroll
        for (int r = 0; r < 4; r++)
          out[(size_t)(row0 + r) * LDO + col] = acc[mi][ni][r] + bv;
      }
    }
}

// ---------------- LSTM recurrence (dual-f16 MFMA, bs=16 per wg) ----------------
template <int NPL>
__global__ __launch_bounds__(512) void k_rec(const float* __restrict__ h0,
                                             const float* __restrict__ c0, int layer) {
  __shared__ __align__(16) _Float16 hh[16][264];
  __shared__ __align__(16) _Float16 hl[16][264];
  const int tid = threadIdx.x, lane = tid & 63, wv = tid >> 6;  // 8 waves
  const int c = lane & 15, q = lane >> 4;
  const int bg = blockIdx.x, d = blockIdx.y;
  const int dirIdx = layer * 2 + d;
  const _Float16* wh = g_whh_h + (size_t)dirIdx * (Gn * Hn);
  const _Float16* wl = g_whh_l + (size_t)dirIdx * (Gn * Hn);
  _Float16* fh = layer ? g_f1_h : g_f0_h;
  _Float16* fl = layer ? g_f1_l : g_f0_l;
  const float* h0p = h0 + ((size_t)dirIdx * Bn + bg * 16) * Hn;
  const float* c0p = c0 + ((size_t)dirIdx * Bn + bg * 16) * Hn;

  for (int i = tid; i < 16 * Hn; i += 512) {
    int row = i >> 8, u = i & 255;
    float v = h0p[row * Hn + u];
    _Float16 h16 = (_Float16)v;
    hh[row][u] = h16;
    hl[row][u] = (_Float16)(v - (float)h16);
  }
  float creg[2][4];
  #pragma unroll
  for (int ni = 0; ni < 2; ni++) {
    int u = (wv + 8 * ni) * 16 + c;
    #pragma unroll
    for (int r = 0; r < 4; r++) creg[ni][r] = c0p[(q * 4 + r) * Hn + u];
  }
  size_t xoff[4];
  #pragma unroll
  for (int r = 0; r < 4; r++)
    xoff[r] = ((size_t)(bg * 16 + q * 4 + r) * Tn) * 2048 + d * 1024 + c;
  __syncthreads();

  for (int t = 0; t < Tn; t++) {
    f32x4 acc[4][2];
    #pragma unroll
    for (int gb = 0; gb < 4; gb++)
      #pragma unroll
      for (int ni = 0; ni < 2; ni++) {
        int coloff = gb * 256 + (wv + 8 * ni) * 16;
        #pragma unroll
        for (int r = 0; r < 4; r++) acc[gb][ni][r] = g_xg[xoff[r] + coloff];
      }
    #pragma unroll
    for (int kc = 0; kc < 8; kc++) {
      const int k = kc * 32 + q * 8;
      f16x8 ah = *(const f16x8*)&hh[c][k];
      f16x8 al;
      if constexpr (NPL > 1) al = *(const f16x8*)&hl[c][k];
      #pragma unroll
      for (int gb = 0; gb < 4; gb++)
        #pragma unroll
        for (int ni = 0; ni < 2; ni++) {
          int nt = gb * 16 + wv + 8 * ni;
          const f16x8 bh = *(const f16x8*)(wh + (size_t)((nt * 8 + kc) * 64 + lane) * 8);
          acc[gb][ni] = mfma_(ah, bh, acc[gb][ni]);
          if constexpr (NPL > 1) {
            const f16x8 bl = *(const f16x8*)(wl + (size_t)((nt * 8 + kc) * 64 + lane) * 8);
            acc[gb][ni] = mfma_(ah, bl, acc[gb][ni]);
            acc[gb][ni] = mfma_(al, bh, acc[gb][ni]);
          }
        }
    }
    __syncthreads();   // all waves done reading h LDS
    int rv[4];
    #pragma unroll
    for (int r = 0; r < 4; r++) {
      int bi = bg * 16 + q * 4 + r;
      rv[r] = (d == 0) ? bi * Tn + t : g_rev[bi * Tn + t];
    }
    #pragma unroll
    for (int ni = 0; ni < 2; ni++) {
      int u = (wv + 8 * ni) * 16 + c;
      #pragma unroll
      for (int r = 0; r < 4; r++) {
        float gi = acc[0][ni][r], gf = acc[1][ni][r];
        float gg = acc[2][ni][r], go = acc[3][ni][r];
        float cn = sigf(gf) * creg[ni][r] + sigf(gi) * tanhf(gg);
        float hn = sigf(go) * tanhf(cn);
        creg[ni][r] = cn;
        _Float16 h16 = (_Float16)hn;
        _Float16 l16 = (_Float16)(hn - (float)h16);
        int row = q * 4 + r;
        hh[row][u] = h16;
        hl[row][u] = l16;
        size_t fo = (size_t)rv[r] * 512 + d * 256 + u;
        fh[fo] = h16;
        fl[fo] = l16;
      }
    }
    __syncthreads();   // new h visible before next step
    #pragma unroll
    for (int r = 0; r < 4; r++) xoff[r] += 2048;
  }
}

// ---------------- CRF alpha scan + Viterbi forward ----------------
__global__ __launch_bounds__(64) void k_scan(const int* __restrict__ lengths,
                                             const int* __restrict__ y_true,
                                             const float* __restrict__ start,
                                             const float* __restrict__ endt,
                                             const float* __restrict__ trans) {
  const int b = blockIdx.x, j = threadIdx.x;
  const int V = lengths[b] * 4;
  const float* em = g_em + (size_t)b * (Tn * 44);
  float tcol[11];
  #pragma unroll
  for (int i = 0; i < 11; i++) tcol[i] = (j < 11) ? trans[i * 11 + j] : 0.f;
  float alpha = (j < 11) ? start[j] + em[j] : -1e30f;
  float score = alpha;
  for (int s = 1; s < V; s++) {
    float e = (j < 11) ? em[s * 11 + j] : 0.f;
    float av[11];
    float m = -1e30f, bestv = -1e30f;
    int bi = 0;
    #pragma unroll
    for (int i = 0; i < 11; i++) {
      float ai = __shfl(alpha, i);
      float si = __shfl(score, i);
      float va = ai + tcol[i];
      float vs = si + tcol[i];
      av[i] = va;
      m = fmaxf(m, va);
      if (vs > bestv) { bestv = vs; bi = i; }  // first-wins argmax
    }
    float sum = 0.f;
    #pragma unroll
    for (int i = 0; i < 11; i++) sum += __expf(av[i] - m);
    alpha = e + m + __logf(sum);
    score = bestv + e;
    if (j < 11) g_hist[(size_t)s * (Bn * NTn) + b * NTn + j] = (unsigned char)bi;
  }
  float ae = (j < 11) ? alpha + endt[j] : -1e30f;
  float se = (j < 11) ? score + endt[j] : -1e30f;
  float m2 = -1e30f;
  #pragma unroll
  for (int i = 0; i < 11; i++) m2 = fmaxf(m2, __shfl(ae, i));
  float s2 = 0.f;
  #pragma unroll
  for (int i = 0; i < 11; i++) s2 += __expf(__shfl(ae, i) - m2);
  float logZ = m2 + __logf(s2);
  float bv = -1e30f;
  int bj = 0;
  #pragma unroll
  for (int i = 0; i < 11; i++) {
    float v = __shfl(se, i);
    if (v > bv) { bv = v; bj = i; }
  }
  const int* y = y_true + (size_t)b * Sn;
  float part = 0.f;
  for (int s = 1 + j; s < V; s += 64) {
    int yp = y[s - 1], yc = y[s];
    part += trans[yp * 11 + yc] + em[s * 11 + yc];
  }
  #pragma unroll
  for (int off = 32; off > 0; off >>= 1) part += __shfl_down(part, off);
  if (j == 0) {
    int y0 = y[0];
    float num = start[y0] + em[y0] + part + endt[y[V - 1]];
    g_llh[b] = num - logZ;
    g_last[b] = bj;
  }
}

__global__ void k_loss(float* out) {
  if (threadIdx.x == 0 && blockIdx.x == 0) {
    float s = 0.f;
    for (int b = 0; b < Bn; b++) s += g_llh[b];
    out[0] = -s / (float)Bn;
  }
}

// ---------------- Viterbi backtrace (single block, LDS-staged chunks) ----------------
__global__ __launch_bounds__(256) void k_back(const int* __restrict__ lengths,
                                              float* __restrict__ out) {
  __shared__ unsigned char hbuf[64 * Bn * NTn];  // 45056 B
  const int tid = threadIdx.x;
  int carry = 0, V = 0;
  if (tid < 64) {
    carry = g_last[tid];
    V = lengths[tid] * 4;
    out[1 + (size_t)tid * Sn + (Sn - 1)] = (float)carry;
  }
  for (int s0 = Sn - 64; s0 >= 0; s0 -= 64) {
    __syncthreads();
    const unsigned int* src = (const unsigned int*)(g_hist + (size_t)s0 * (Bn * NTn));
    unsigned int* dst = (unsigned int*)hbuf;
    for (int i = tid; i < 64 * Bn * NTn / 4; i += 256) dst[i] = src[i];
    __syncthreads();
    if (tid < 64) {
      for (int s = s0 + 63; s >= s0 && s >= 1; s--) {
        int pr = hbuf[(s - s0) * (Bn * NTn) + tid * NTn + carry];
        if (s < V) carry = pr;
        out[1 + (size_t)tid * Sn + (s - 1)] = (float)carry;
      }
    }
  }
}

// ---------------- host ----------------
extern "C" void kernel_launch(void* const* d_in, const int* in_sizes, int n_in,
                              void* d_out, int out_size, void* d_ws, size_t ws_size,
                              hipStream_t stream) {
  (void)in_sizes; (void)n_in; (void)d_ws; (void)ws_size; (void)out_size;
  const float* x        = (const float*)d_in[0];
  const int*   y_true   = (const int*)d_in[1];
  const int*   lengths  = (const int*)d_in[2];
  const float* h0       = (const float*)d_in[3];
  const float* c0       = (const float*)d_in[4];
  const float* w_ih_l0  = (const float*)d_in[5];
  const float* w_hh_l0  = (const float*)d_in[6];
  const float* b_l0     = (const float*)d_in[7];
  const float* w_ih_l0r = (const float*)d_in[8];
  const float* w_hh_l0r = (const float*)d_in[9];
  const float* b_l0r    = (const float*)d_in[10];
  const float* w_ih_l1  = (const float*)d_in[11];
  const float* w_hh_l1  = (const float*)d_in[12];
  const float* b_l1     = (const float*)d_in[13];
  const float* w_ih_l1r = (const float*)d_in[14];
  const float* w_hh_l1r = (const float*)d_in[15];
  const float* b_l1r    = (const float*)d_in[16];
  const float* w_out    = (const float*)d_in[17];
  const float* b_out    = (const float*)d_in[18];
  const float* start_t  = (const float*)d_in[19];
  const float* end_t    = (const float*)d_in[20];
  const float* trans    = (const float*)d_in[21];
  float* out = (float*)d_out;

  auto gs = [](int n) { return dim3((n + 255) / 256); };
  dim3 b256(256);

  // weight prep
  k_wswz<<<gs(4 * Gn * Hn), b256, 0, stream>>>(w_hh_l0, w_hh_l0r, w_hh_l1, w_hh_l1r);
  k_split<<<gs(131072), b256, 0, stream>>>(w_ih_l0, 1, 0, 131072);
  k_split<<<gs(131072), b256, 0, stream>>>(w_ih_l0r, 1, 131072, 131072);
  k_split<<<gs(524288), b256, 0, stream>>>(w_ih_l1, 2, 0, 524288);
  k_split<<<gs(524288), b256, 0, stream>>>(w_ih_l1r, 2, 524288, 524288);
  k_split<<<gs(22528), b256, 0, stream>>>(w_out, 3, 0, 22528);
  k_copy<<<gs(1024), b256, 0, stream>>>(b_l0, 0, 0, 1024);
  k_copy<<<gs(1024), b256, 0, stream>>>(b_l0r, 0, 1024, 1024);
  k_copy<<<gs(1024), b256, 0, stream>>>(b_l1, 1, 0, 1024);
  k_copy<<<gs(1024), b256, 0, stream>>>(b_l1r, 1, 1024, 1024);
  k_copy<<<gs(44), b256, 0, stream>>>(b_out, 2, 0, 44);
  k_pad<<<gs(2048), b256, 0, stream>>>();
  k_rev<<<gs(BT), b256, 0, stream>>>(lengths);
  k_xpose<<<dim3(Tn / 32, Fn / 32, Bn), dim3(32, 8), 0, stream>>>(x);

  // layer 0
  k_gemm<0, 3><<<dim3(BT / 128, 16), b256, 0, stream>>>();
  k_rec<3><<<dim3(4, 2), dim3(512), 0, stream>>>(h0, c0, 0);
  // layer 1
  k_gemm<1, 3><<<dim3(BT / 128, 16), b256, 0, stream>>>();
  k_rec<3><<<dim3(4, 2), dim3(512), 0, stream>>>(h0, c0, 1);
  // emissions
  k_gemm<2, 3><<<dim3(BT / 128, 1), b256, 0, stream>>>();
  // CRF + viterbi
  k_scan<<<dim3(Bn), dim3(64), 0, stream>>>(lengths, y_true, start_t, end_t, trans);
  k_loss<<<dim3(1), dim3(64), 0, stream>>>(out);
  k_back<<<dim3(1), b256, 0, stream>>>(lengths, out);
}